// Round 4
// baseline (1495.780 us; speedup 1.0000x reference)
//
#include <hip/hip_runtime.h>
#include <stdint.h>

#define T_LEN 8196
#define LOG2E 1.4426950408889634f
#define LN2   0.6931471805599453f
#define INF2  1.4426950e10f   /* 1e10 * log2(e): INF in base-2-scaled units */
#define PD_LD 2080            /* padded E row stride: 16 left + 2048 + 16 right */
#define PD_OFF 16

#define NROW 16               /* rows per lane */
#define NBLK 2                /* DTW blocks; NROW*64*NBLK = 2048 */

// ---------------------------------------------------------------- helpers
__device__ __forceinline__ float fexp2(float x) {
#if __has_builtin(__builtin_amdgcn_exp2f)
    return __builtin_amdgcn_exp2f(x);
#else
    return __expf(x * LN2);
#endif
}
__device__ __forceinline__ float flog2(float x) {
#if __has_builtin(__builtin_amdgcn_logf)
    return __builtin_amdgcn_logf(x);   // v_log_f32 is base-2
#else
    return __logf(x) * LOG2E;
#endif
}
__device__ __forceinline__ float sigm(float x) { return 1.0f / (1.0f + __expf(-x)); }
__device__ __forceinline__ float tanh_f(float x) {
    x = fminf(fmaxf(x, -15.0f), 15.0f);
    float e = __expf(2.0f * x);
    return (e - 1.0f) / (e + 1.0f);
}
/* async global->LDS, 16 B per lane; LDS dest = wave-uniform base + lane*16 */
__device__ __forceinline__ void gload16(const void* g, void* l) {
    __builtin_amdgcn_global_load_lds(
        (const __attribute__((address_space(1))) uint32_t*)g,
        (__attribute__((address_space(3))) uint32_t*)l, 16, 0, 0);
}

// ------------------------------------------- prep: transpose weights
__global__ void k_prep(const float* __restrict__ Wih1, const float* __restrict__ Whh1,
                       const float* __restrict__ Wih2, const float* __restrict__ Whh2,
                       float* __restrict__ wt) {
    int gid = blockIdx.x * 256 + threadIdx.x;
    if (gid >= 175104) return;
    if (gid < 27648) {
        int k = gid / 384, g = gid % 384;
        wt[gid] = Wih1[g * 72 + k];
    } else if (gid < 76800) {
        int r = gid - 27648; int k = r / 384, g = r % 384;
        wt[gid] = Whh1[g * 128 + k];
    } else if (gid < 125952) {
        int r = gid - 76800; int k = r / 384, g = r % 384;
        wt[gid] = Wih2[g * 128 + k];
    } else {
        int r = gid - 125952; int k = r / 384, g = r % 384;
        wt[gid] = Whh2[g * 128 + k];
    }
}

// ------------------------------------------- GRU features (unchanged)
__global__ __launch_bounds__(256)
void k_gru(const float* __restrict__ X, const float* __restrict__ Y,
           const float* __restrict__ wt,
           const float* __restrict__ bih1, const float* __restrict__ bhh1,
           const float* __restrict__ bih2, const float* __restrict__ bhh2,
           const float* __restrict__ W1, const float* __restrict__ b1,
           float* __restrict__ fbuf) {
    __shared__ __align__(16) float xb[72 * 20];
    __shared__ __align__(16) float h1l[128 * 20];
    __shared__ __align__(16) float h2l[128 * 20];

    const int tid = threadIdx.x;
    const int u = tid & 127;
    const int w0 = (tid >> 7) * 8;
    const int bx = blockIdx.x;
    const int seq = bx >> 7;
    const int wbase = (bx & 127) << 4;
    const float* xp = seq ? Y : X;

    const float* wih1 = wt;
    const float* whh1 = wt + 27648;
    const float* wih2 = wt + 76800;
    const float* whh2 = wt + 125952;

    const float br1  = bih1[u] + bhh1[u];
    const float bz1  = bih1[128 + u] + bhh1[128 + u];
    const float bni1 = bih1[256 + u];
    const float bnh1 = bhh1[256 + u];
    const float br2  = bih2[u] + bhh2[u];
    const float bz2  = bih2[128 + u] + bhh2[128 + u];
    const float bni2 = bih2[256 + u];
    const float bnh2 = bhh2[256 + u];

    float h1r[8], h2r[8];
#pragma unroll
    for (int j = 0; j < 8; ++j) { h1r[j] = 0.f; h2r[j] = 0.f; }
    for (int e = tid; e < 128 * 20; e += 256) { h1l[e] = 0.f; h2l[e] = 0.f; }
    __syncthreads();

    for (int t = 0; t < 8; ++t) {
        for (int e = tid; e < 72 * 16; e += 256) {
            int k = e >> 4, w = e & 15;
            int jj = k / 3, c = k - jj * 3;
            xb[k * 20 + w] = xp[jj * (3 * T_LEN) + c * T_LEN + ((wbase + w) << 2) + t];
        }
        __syncthreads();

        float ar[8], az[8], ai[8], ah[8];
#pragma unroll
        for (int j = 0; j < 8; ++j) { ar[j] = br1; az[j] = bz1; ai[j] = bni1; ah[j] = bnh1; }
        for (int k = 0; k < 72; ++k) {
            float wr = wih1[k * 384 + u];
            float wz = wih1[k * 384 + 128 + u];
            float wn = wih1[k * 384 + 256 + u];
            const float4 x0 = *(const float4*)&xb[k * 20 + w0];
            const float4 x1 = *(const float4*)&xb[k * 20 + w0 + 4];
            float xv[8] = {x0.x, x0.y, x0.z, x0.w, x1.x, x1.y, x1.z, x1.w};
#pragma unroll
            for (int j = 0; j < 8; ++j) {
                ar[j] = fmaf(wr, xv[j], ar[j]);
                az[j] = fmaf(wz, xv[j], az[j]);
                ai[j] = fmaf(wn, xv[j], ai[j]);
            }
        }
        for (int k = 0; k < 128; ++k) {
            float wr = whh1[k * 384 + u];
            float wz = whh1[k * 384 + 128 + u];
            float wn = whh1[k * 384 + 256 + u];
            const float4 x0 = *(const float4*)&h1l[k * 20 + w0];
            const float4 x1 = *(const float4*)&h1l[k * 20 + w0 + 4];
            float xv[8] = {x0.x, x0.y, x0.z, x0.w, x1.x, x1.y, x1.z, x1.w};
#pragma unroll
            for (int j = 0; j < 8; ++j) {
                ar[j] = fmaf(wr, xv[j], ar[j]);
                az[j] = fmaf(wz, xv[j], az[j]);
                ah[j] = fmaf(wn, xv[j], ah[j]);
            }
        }
        __syncthreads();
#pragma unroll
        for (int j = 0; j < 8; ++j) {
            float r = sigm(ar[j]);
            float z = sigm(az[j]);
            float n = tanh_f(ai[j] + r * ah[j]);
            h1r[j] = (1.f - z) * n + z * h1r[j];
        }
#pragma unroll
        for (int j = 0; j < 8; ++j) h1l[u * 20 + w0 + j] = h1r[j];
        __syncthreads();

#pragma unroll
        for (int j = 0; j < 8; ++j) { ar[j] = br2; az[j] = bz2; ai[j] = bni2; ah[j] = bnh2; }
        for (int k = 0; k < 128; ++k) {
            float wr = wih2[k * 384 + u];
            float wz = wih2[k * 384 + 128 + u];
            float wn = wih2[k * 384 + 256 + u];
            const float4 x0 = *(const float4*)&h1l[k * 20 + w0];
            const float4 x1 = *(const float4*)&h1l[k * 20 + w0 + 4];
            float xv[8] = {x0.x, x0.y, x0.z, x0.w, x1.x, x1.y, x1.z, x1.w};
#pragma unroll
            for (int j = 0; j < 8; ++j) {
                ar[j] = fmaf(wr, xv[j], ar[j]);
                az[j] = fmaf(wz, xv[j], az[j]);
                ai[j] = fmaf(wn, xv[j], ai[j]);
            }
        }
        for (int k = 0; k < 128; ++k) {
            float wr = whh2[k * 384 + u];
            float wz = whh2[k * 384 + 128 + u];
            float wn = whh2[k * 384 + 256 + u];
            const float4 x0 = *(const float4*)&h2l[k * 20 + w0];
            const float4 x1 = *(const float4*)&h2l[k * 20 + w0 + 4];
            float xv[8] = {x0.x, x0.y, x0.z, x0.w, x1.x, x1.y, x1.z, x1.w};
#pragma unroll
            for (int j = 0; j < 8; ++j) {
                ar[j] = fmaf(wr, xv[j], ar[j]);
                az[j] = fmaf(wz, xv[j], az[j]);
                ah[j] = fmaf(wn, xv[j], ah[j]);
            }
        }
        __syncthreads();
#pragma unroll
        for (int j = 0; j < 8; ++j) {
            float r = sigm(ar[j]);
            float z = sigm(az[j]);
            float n = tanh_f(ai[j] + r * ah[j]);
            h2r[j] = (1.f - z) * n + z * h2r[j];
        }
#pragma unroll
        for (int j = 0; j < 8; ++j) h2l[u * 20 + w0 + j] = h2r[j];
        __syncthreads();
    }

    for (int idx = tid; idx < 16 * 30; idx += 256) {
        int w = idx / 30, ff = idx - w * 30;
        float acc = b1[ff];
        for (int k = 0; k < 128; ++k) acc = fmaf(h2l[k * 20 + w], W1[ff * 128 + k], acc);
        fbuf[(seq * 2048 + wbase + w) * 32 + ff] = acc;
    }
}

// ------------------------------------------- pairwise sqdist -> E = exp(-D), padded
__global__ __launch_bounds__(256)
void k_pair(const float* __restrict__ fbuf, float* __restrict__ Ep) {
    __shared__ float f1t[64 * 33];
    __shared__ float f2t[64 * 33];
    const int tid = threadIdx.x;
    const int i0 = blockIdx.y * 64, j0 = blockIdx.x * 64;
    for (int e = tid; e < 64 * 32; e += 256) {
        int r = e >> 5, c = e & 31;
        f1t[r * 33 + c] = fbuf[(i0 + r) * 32 + c];
        f2t[r * 33 + c] = fbuf[(2048 + j0 + r) * 32 + c];
    }
    __syncthreads();
    const int tx = tid & 15, ty = tid >> 4;
    float acc[4][4];
#pragma unroll
    for (int r = 0; r < 4; ++r)
#pragma unroll
        for (int c = 0; c < 4; ++c) acc[r][c] = 0.f;
    for (int k = 0; k < 30; ++k) {
        float a[4], b[4];
#pragma unroll
        for (int r = 0; r < 4; ++r) a[r] = f1t[(ty * 4 + r) * 33 + k];
#pragma unroll
        for (int c = 0; c < 4; ++c) b[c] = f2t[(tx * 4 + c) * 33 + k];
#pragma unroll
        for (int r = 0; r < 4; ++r)
#pragma unroll
            for (int c = 0; c < 4; ++c) {
                float d = a[r] - b[c];
                acc[r][c] = fmaf(d, d, acc[r][c]);
            }
    }
#pragma unroll
    for (int r = 0; r < 4; ++r) {
        float4 v = make_float4(__expf(-acc[r][0]), __expf(-acc[r][1]),
                               __expf(-acc[r][2]), __expf(-acc[r][3]));
        *(float4*)&Ep[(size_t)(i0 + ty * 4 + r) * PD_LD + PD_OFF + j0 + tx * 4] = v;
    }
}

// ------------------------------------------- softDTW wavefront, EXP-DOMAIN
// R11: LDS-staged E tiles (global_load_lds, no VGPR round-trip) + r-outer
// compute. R9/R10 diagnosis: register double-buffer is un-schedulable (reg
// recycling forces prefetch loads to issue late => ~3000 cy exposed latency
// per macro). Here:
//  * tile(m+1) prefetched into ldsE[(m+1)&1] at macro m top via 32x
//    global_load_lds width=16 (no destination VGPRs => issue is a batch).
//  * every macro issues exactly 40 VMEM ops (32 tile + 8-slot: ring loads
//    for b>0 / lane63 exchanges incl. dummy-slot for b==0), so a manual
//    s_waitcnt vmcnt(8) at macro top forces the CURRENT tile complete while
//    leaving the newest 8 (ring/stores) in flight. vmcnt retires oldest-
//    first (m135). Backoff polls self-heal the count (their consumption
//    drains vmcnt ~0).
//  * compute r-outer/c-inner: each E element used once; rows streamed from
//    LDS 2x ds_read_b128 with a 4-row pipeline (~24 live floats, no tile
//    in registers). Math identical: cell = E*(diag+up+left), diag for c=0
//    carried via saved old-W.
#define DTW_STEP(E, C)                                                           \
    { float off = (E) * (d + up[C]); w = fmaf((E), left, off);                   \
      d = up[C]; up[C] = w; left = w; }

#define DTW_MACRO(CURB, PFB, PVC, PVI, M)                                        \
  {                                                                              \
    const int m = (M);                                                           \
    asm volatile("s_waitcnt vmcnt(8)" ::: "memory");                             \
    { /* prefetch tile m+1 -> ldsE[PFB] (32 VMEM) */                             \
        int bs = 8 * (m + 1 - lane);                                             \
        bs = bs < -16 ? -16 : (bs > 2048 ? 2048 : bs);                           \
        const float* s0 = rp0 + bs;                                              \
        _Pragma("unroll")                                                        \
        for (int r = 0; r < NROW; ++r) {                                         \
            const float* s = s0 + (size_t)r * PD_LD;                             \
            gload16(s,     &ldsE[PFB][(2 * r) * 256 + (lane << 2)]);             \
            gload16(s + 4, &ldsE[PFB][(2 * r + 1) * 256 + (lane << 2)]);         \
        }                                                                        \
    }                                                                            \
    if (b > 0 && lane == 0) {   /* ring loads for macro m+2 (8 VMEM) */          \
        _Pragma("unroll")                                                        \
        for (int u = 0; u < 8; ++u) {                                            \
            int jc = 8 * (m + 2) + u; jc = jc > 2047 ? 2047 : jc;                \
            PVI[u] = __hip_atomic_load(&bIn[jc], __ATOMIC_RELAXED,               \
                                       __HIP_MEMORY_SCOPE_AGENT);                \
        }                                                                        \
    }                                                                            \
    float Tw[8];                                                                 \
    _Pragma("unroll")                                                            \
    for (int c = 0; c < 8; ++c) Tw[c] = fexp2(Sc - sIn[c]);                      \
    float Td = fexp2(Sc - carryA);                                               \
    const float* cb = &ldsE[CURB][0];                                            \
    float4 q0[4], q1[4];                                                         \
    _Pragma("unroll")                                                            \
    for (int r = 0; r < 4; ++r) {                                                \
        q0[r] = *(const float4*)(cb + (2 * r) * 256 + (lane << 2));              \
        q1[r] = *(const float4*)(cb + (2 * r + 1) * 256 + (lane << 2));          \
    }                                                                            \
    float up[8];                                                                 \
    _Pragma("unroll")                                                            \
    for (int c = 0; c < 8; ++c) up[c] = Tw[c];                                   \
    float dg = Td;                                                               \
    _Pragma("unroll")                                                            \
    for (int r = 0; r < NROW; ++r) {                                             \
        const int rb = r & 3;                                                    \
        float e0 = q0[rb].x, e1 = q0[rb].y, e2 = q0[rb].z, e3 = q0[rb].w;        \
        float e4 = q1[rb].x, e5 = q1[rb].y, e6 = q1[rb].z, e7 = q1[rb].w;        \
        if (r + 4 < NROW) {                                                      \
            q0[rb] = *(const float4*)(cb + (2 * (r + 4)) * 256 + (lane << 2));   \
            q1[rb] = *(const float4*)(cb + (2 * (r + 4) + 1) * 256 + (lane << 2)); \
        }                                                                        \
        float left = W[r];                                                       \
        float dgn  = W[r];                                                       \
        float d = dg;                                                            \
        float w;                                                                 \
        DTW_STEP(e0, 0) DTW_STEP(e1, 1) DTW_STEP(e2, 2) DTW_STEP(e3, 3)          \
        DTW_STEP(e4, 4) DTW_STEP(e5, 5) DTW_STEP(e6, 6) DTW_STEP(e7, 7)          \
        W[r] = w;                                                                \
        dg = dgn;                                                                \
    }                                                                            \
    float blog[8];                                                               \
    _Pragma("unroll")                                                            \
    for (int c = 0; c < 8; ++c) blog[c] = fminf(Sc - flog2(up[c]), INF2);        \
    carryA = sIn[7];                                                             \
    if (lane == 63) {                                                            \
        if (b < NBLK - 1) {   /* 8 VMEM, constant count via dummy slot */        \
            _Pragma("unroll")                                                    \
            for (int c = 0; c < 8; ++c) {                                        \
                int j = 8 * (m - 63) + c;                                        \
                bool v = (j >= 0) && (j < 2048);                                 \
                uint64_t pk = ((uint64_t)(uint32_t)j << 32) |                    \
                              (uint64_t)__float_as_uint(blog[c]);                \
                uint64_t* dst = v ? (bOut + j) : (bDum + c);                     \
                (void)__hip_atomic_exchange(dst, pk, __ATOMIC_RELAXED,           \
                                            __HIP_MEMORY_SCOPE_AGENT);           \
            }                                                                    \
        } else if (8 * (m - 63) + 7 == 2047) {                                   \
            res = blog[7];                                                       \
        }                                                                        \
    }                                                                            \
    float sh[8];                                                                 \
    _Pragma("unroll")                                                            \
    for (int c = 0; c < 8; ++c) sh[c] = __shfl_up(blog[c], 1);                   \
    if (lane > 0) {                                                              \
        _Pragma("unroll")                                                        \
        for (int c = 0; c < 8; ++c) sIn[c] = sh[c];                              \
    } else if (b == 0) {                                                         \
        _Pragma("unroll")                                                        \
        for (int c = 0; c < 8; ++c) sIn[c] = INF2;                               \
    } else {   /* consume ring slot PVC = boundary for macro m+1 */              \
        bool again = false;                                                      \
        _Pragma("unroll")                                                        \
        for (int u = 0; u < 8; ++u) {                                            \
            int jc = 8 * (m + 1) + u; jc = jc > 2047 ? 2047 : jc;                \
            if ((uint32_t)(PVC[u] >> 32) != (uint32_t)jc) again = true;          \
        }                                                                        \
        while (again) {   /* rare: fell on frontier; long backoff */             \
            __builtin_amdgcn_s_sleep(32);                                        \
            _Pragma("unroll")                                                    \
            for (int u = 0; u < 8; ++u) {                                        \
                int jc = 8 * (m + 1) + u; jc = jc > 2047 ? 2047 : jc;            \
                PVC[u] = __hip_atomic_load(&bIn[jc], __ATOMIC_RELAXED,           \
                                           __HIP_MEMORY_SCOPE_AGENT);            \
            }                                                                    \
            again = false;                                                       \
            _Pragma("unroll")                                                    \
            for (int u = 0; u < 8; ++u) {                                        \
                int jc = 8 * (m + 1) + u; jc = jc > 2047 ? 2047 : jc;            \
                if ((uint32_t)(PVC[u] >> 32) != (uint32_t)jc) again = true;      \
            }                                                                    \
        }                                                                        \
        _Pragma("unroll")                                                        \
        for (int u = 0; u < 8; ++u) sIn[u] = __uint_as_float((uint32_t)PVC[u]);  \
    }                                                                            \
    { /* scale update (uses NEXT macro's incoming mins) */                       \
        float mn = fminf(fminf(fminf(sIn[0], sIn[1]), fminf(sIn[2], sIn[3])),    \
                         fminf(fminf(sIn[4], sIn[5]), fminf(sIn[6], sIn[7])));   \
        float t0 = fmaxf(W[0], W[1]),   t1 = fmaxf(W[2], W[3]);                  \
        float t2 = fmaxf(W[4], W[5]),   t3 = fmaxf(W[6], W[7]);                  \
        float t4 = fmaxf(W[8], W[9]),   t5 = fmaxf(W[10], W[11]);                \
        float t6 = fmaxf(W[12], W[13]), t7 = fmaxf(W[14], W[15]);                \
        float wmax = fmaxf(fmaxf(fmaxf(t0, t1), fmaxf(t2, t3)),                  \
                           fmaxf(fmaxf(t4, t5), fmaxf(t6, t7)));                 \
        float Sc_new;                                                            \
        if (wmax > 0.f) {                                                        \
            int e = (int)((__float_as_uint(wmax) >> 23) & 0xFFu) - 127;          \
            Sc_new = fminf(Sc - (float)e, mn + 100.f);                           \
        } else {                                                                 \
            Sc_new = fminf(mn, 1e9f);                                            \
        }                                                                        \
        int dd = (int)fmaxf(fminf(Sc_new - Sc, 999.f), -999.f);                  \
        _Pragma("unroll")                                                        \
        for (int r = 0; r < NROW; ++r) W[r] = ldexpf(W[r], dd);                  \
        Sc = Sc_new;                                                             \
    }                                                                            \
  }

__global__ __launch_bounds__(64, 1)
void k_dtw(const float* __restrict__ Ep, uint64_t* bndG, float* __restrict__ out) {
    __shared__ __align__(16) float ldsE[2][8192];   // 2 x 32 KB E-tile buffers

    const int b = blockIdx.x;
    const int lane = threadIdx.x;
    const int r0 = b * (NROW * 64) + lane * NROW;
    const uint64_t* bIn = bndG + (size_t)(b - 1) * 2048;
    uint64_t* bOut = bndG + (size_t)b * 2048;
    uint64_t* bDum = bndG + 2 * 2048;   // unused region (b==1's bOut, never read)
    const float* rp0 = Ep + (size_t)r0 * PD_LD + PD_OFF;

    float W[NROW];
#pragma unroll
    for (int r = 0; r < NROW; ++r) W[r] = 0.f;
    float Sc = 0.f;
    float carryA = (b == 0 && lane == 0) ? 0.f : INF2;  // seed: A(-1,-1)=0
    float res = 0.f;
    float sIn[8];
#pragma unroll
    for (int c = 0; c < 8; ++c) sIn[c] = INF2;

    uint64_t pvs0[8], pvs1[8];
#pragma unroll
    for (int u = 0; u < 8; ++u) { pvs0[u] = 0; pvs1[u] = 0; }

    if (b > 0 && lane == 0) {
        // --- startup SLACK: wait until producer is ~64 cols past our need
        {
            uint64_t p = __hip_atomic_load(&bIn[71], __ATOMIC_RELAXED,
                                           __HIP_MEMORY_SCOPE_AGENT);
            while ((uint32_t)(p >> 32) != 71u) {
                __builtin_amdgcn_s_sleep(8);
                p = __hip_atomic_load(&bIn[71], __ATOMIC_RELAXED,
                                      __HIP_MEMORY_SCOPE_AGENT);
            }
        }
        // --- blocking poll for macro-0 boundary (cols 0..7) + scale seed
        uint64_t pv[8];
        bool again = true;
        while (again) {
#pragma unroll
            for (int u = 0; u < 8; ++u)
                pv[u] = __hip_atomic_load(&bIn[u], __ATOMIC_RELAXED,
                                          __HIP_MEMORY_SCOPE_AGENT);
            again = false;
#pragma unroll
            for (int u = 0; u < 8; ++u)
                if ((uint32_t)(pv[u] >> 32) != (uint32_t)u) again = true;
            if (again) __builtin_amdgcn_s_sleep(2);
        }
        float mn = INF2;
#pragma unroll
        for (int u = 0; u < 8; ++u) {
            sIn[u] = __uint_as_float((uint32_t)pv[u]);
            mn = fminf(mn, sIn[u]);
        }
        Sc = fminf(mn, 1e9f);
    }

    { // prologue: issue tile(0) -> ldsE[0] (32 VMEM)
        int bs = 8 * (0 - lane);
        bs = bs < -16 ? -16 : bs;
        const float* s0 = rp0 + bs;
#pragma unroll
        for (int r = 0; r < NROW; ++r) {
            const float* s = s0 + (size_t)r * PD_LD;
            gload16(s,     &ldsE[0][(2 * r) * 256 + (lane << 2)]);
            gload16(s + 4, &ldsE[0][(2 * r + 1) * 256 + (lane << 2)]);
        }
    }
    // prologue 8-slot (keeps the per-macro VMEM pattern ...32,8,32,8...):
    if (b > 0) {
        if (lane == 0) {   // prime ring slot 0: boundary for macro 1 (cols 8..15)
#pragma unroll
            for (int u = 0; u < 8; ++u)
                pvs0[u] = __hip_atomic_load(&bIn[8 + u], __ATOMIC_RELAXED,
                                            __HIP_MEMORY_SCOPE_AGENT);
        }
    } else if (lane == 0) {   // b==0: 8 dummy exchanges to pad the count
#pragma unroll
        for (int u = 0; u < 8; ++u)
            (void)__hip_atomic_exchange(bDum + u, (uint64_t)0, __ATOMIC_RELAXED,
                                        __HIP_MEMORY_SCOPE_AGENT);
    }

    // 320 macro-steps of 8 cols (lane63 hits col 2047 at m=318)
    for (int mm = 0; mm < 320; mm += 2) {
        DTW_MACRO(0, 1, pvs0, pvs1, mm);
        DTW_MACRO(1, 0, pvs1, pvs0, mm + 1);
    }

    if (b == NBLK - 1 && lane == 63) out[0] = res * LN2;   // back to base-e units
}

// ------------------------------------------- launch
extern "C" void kernel_launch(void* const* d_in, const int* in_sizes, int n_in,
                              void* d_out, int out_size, void* d_ws, size_t ws_size,
                              hipStream_t stream) {
    const float* X    = (const float*)d_in[0];
    const float* Y    = (const float*)d_in[1];
    const float* Wih1 = (const float*)d_in[2];
    const float* Whh1 = (const float*)d_in[3];
    const float* bih1 = (const float*)d_in[4];
    const float* bhh1 = (const float*)d_in[5];
    const float* Wih2 = (const float*)d_in[6];
    const float* Whh2 = (const float*)d_in[7];
    const float* bih2 = (const float*)d_in[8];
    const float* bhh2 = (const float*)d_in[9];
    const float* W1   = (const float*)d_in[10];
    const float* b1   = (const float*)d_in[11];
    float* out = (float*)d_out;

    // Layout (floats). wt overlaps Ep's tail (dead after k_gru; k_pair
    // overwrites all of Ep afterwards). ~17.7 MB total.
    float* ws   = (float*)d_ws;
    float* fbuf = ws;                            // 131072 floats
    uint64_t* bndG = (uint64_t*)(ws + 131072);   // 7*2048 u64 = 28672 floats
    float* Ep   = ws + 131072 + 28672;           // 2048*2080 = 4259840 floats
    float* wt   = Ep + 4259840 - 175104;         // overlapped tail

    k_prep<<<684, 256, 0, stream>>>(Wih1, Whh1, Wih2, Whh2, wt);
    k_gru<<<256, 256, 0, stream>>>(X, Y, wt, bih1, bhh1, bih2, bhh2, W1, b1, fbuf);
    k_pair<<<dim3(32, 32), 256, 0, stream>>>(fbuf, Ep);
    k_dtw<<<NBLK, 64, 0, stream>>>(Ep, bndG, out);
}

// Round 6
// 1004.619 us; speedup vs baseline: 1.4889x; 1.4889x over previous
//
#include <hip/hip_runtime.h>
#include <stdint.h>

#define T_LEN 8196
#define LOG2E 1.4426950408889634f
#define LN2   0.6931471805599453f
#define INF2  1.4426950e10f   /* 1e10 * log2(e): INF in base-2-scaled units */
#define PD_LD 2080            /* padded E row stride: 16 left + 2048 + 16 right */
#define PD_OFF 16

// ---------------------------------------------------------------- helpers
__device__ __forceinline__ float fexp2(float x) {
#if __has_builtin(__builtin_amdgcn_exp2f)
    return __builtin_amdgcn_exp2f(x);
#else
    return __expf(x * LN2);
#endif
}
__device__ __forceinline__ float flog2(float x) {
#if __has_builtin(__builtin_amdgcn_logf)
    return __builtin_amdgcn_logf(x);   // v_log_f32 is base-2
#else
    return __logf(x) * LOG2E;
#endif
}
__device__ __forceinline__ float sigm(float x) { return 1.0f / (1.0f + __expf(-x)); }
__device__ __forceinline__ float tanh_f(float x) {
    x = fminf(fmaxf(x, -15.0f), 15.0f);
    float e = __expf(2.0f * x);
    return (e - 1.0f) / (e + 1.0f);
}

// ------------------------------------------- prep: transpose weights
__global__ void k_prep(const float* __restrict__ Wih1, const float* __restrict__ Whh1,
                       const float* __restrict__ Wih2, const float* __restrict__ Whh2,
                       float* __restrict__ wt) {
    int gid = blockIdx.x * 256 + threadIdx.x;
    if (gid >= 175104) return;
    if (gid < 27648) {
        int k = gid / 384, g = gid % 384;
        wt[gid] = Wih1[g * 72 + k];
    } else if (gid < 76800) {
        int r = gid - 27648; int k = r / 384, g = r % 384;
        wt[gid] = Whh1[g * 128 + k];
    } else if (gid < 125952) {
        int r = gid - 76800; int k = r / 384, g = r % 384;
        wt[gid] = Wih2[g * 128 + k];
    } else {
        int r = gid - 125952; int k = r / 384, g = r % 384;
        wt[gid] = Whh2[g * 128 + k];
    }
}

// ------------------------------------------- GRU features (unchanged)
__global__ __launch_bounds__(256)
void k_gru(const float* __restrict__ X, const float* __restrict__ Y,
           const float* __restrict__ wt,
           const float* __restrict__ bih1, const float* __restrict__ bhh1,
           const float* __restrict__ bih2, const float* __restrict__ bhh2,
           const float* __restrict__ W1, const float* __restrict__ b1,
           float* __restrict__ fbuf) {
    __shared__ __align__(16) float xb[72 * 20];
    __shared__ __align__(16) float h1l[128 * 20];
    __shared__ __align__(16) float h2l[128 * 20];

    const int tid = threadIdx.x;
    const int u = tid & 127;
    const int w0 = (tid >> 7) * 8;
    const int bx = blockIdx.x;
    const int seq = bx >> 7;
    const int wbase = (bx & 127) << 4;
    const float* xp = seq ? Y : X;

    const float* wih1 = wt;
    const float* whh1 = wt + 27648;
    const float* wih2 = wt + 76800;
    const float* whh2 = wt + 125952;

    const float br1  = bih1[u] + bhh1[u];
    const float bz1  = bih1[128 + u] + bhh1[128 + u];
    const float bni1 = bih1[256 + u];
    const float bnh1 = bhh1[256 + u];
    const float br2  = bih2[u] + bhh2[u];
    const float bz2  = bih2[128 + u] + bhh2[128 + u];
    const float bni2 = bih2[256 + u];
    const float bnh2 = bhh2[256 + u];

    float h1r[8], h2r[8];
#pragma unroll
    for (int j = 0; j < 8; ++j) { h1r[j] = 0.f; h2r[j] = 0.f; }
    for (int e = tid; e < 128 * 20; e += 256) { h1l[e] = 0.f; h2l[e] = 0.f; }
    __syncthreads();

    for (int t = 0; t < 8; ++t) {
        for (int e = tid; e < 72 * 16; e += 256) {
            int k = e >> 4, w = e & 15;
            int jj = k / 3, c = k - jj * 3;
            xb[k * 20 + w] = xp[jj * (3 * T_LEN) + c * T_LEN + ((wbase + w) << 2) + t];
        }
        __syncthreads();

        float ar[8], az[8], ai[8], ah[8];
#pragma unroll
        for (int j = 0; j < 8; ++j) { ar[j] = br1; az[j] = bz1; ai[j] = bni1; ah[j] = bnh1; }
        for (int k = 0; k < 72; ++k) {
            float wr = wih1[k * 384 + u];
            float wz = wih1[k * 384 + 128 + u];
            float wn = wih1[k * 384 + 256 + u];
            const float4 x0 = *(const float4*)&xb[k * 20 + w0];
            const float4 x1 = *(const float4*)&xb[k * 20 + w0 + 4];
            float xv[8] = {x0.x, x0.y, x0.z, x0.w, x1.x, x1.y, x1.z, x1.w};
#pragma unroll
            for (int j = 0; j < 8; ++j) {
                ar[j] = fmaf(wr, xv[j], ar[j]);
                az[j] = fmaf(wz, xv[j], az[j]);
                ai[j] = fmaf(wn, xv[j], ai[j]);
            }
        }
        for (int k = 0; k < 128; ++k) {
            float wr = whh1[k * 384 + u];
            float wz = whh1[k * 384 + 128 + u];
            float wn = whh1[k * 384 + 256 + u];
            const float4 x0 = *(const float4*)&h1l[k * 20 + w0];
            const float4 x1 = *(const float4*)&h1l[k * 20 + w0 + 4];
            float xv[8] = {x0.x, x0.y, x0.z, x0.w, x1.x, x1.y, x1.z, x1.w};
#pragma unroll
            for (int j = 0; j < 8; ++j) {
                ar[j] = fmaf(wr, xv[j], ar[j]);
                az[j] = fmaf(wz, xv[j], az[j]);
                ah[j] = fmaf(wn, xv[j], ah[j]);
            }
        }
        __syncthreads();
#pragma unroll
        for (int j = 0; j < 8; ++j) {
            float r = sigm(ar[j]);
            float z = sigm(az[j]);
            float n = tanh_f(ai[j] + r * ah[j]);
            h1r[j] = (1.f - z) * n + z * h1r[j];
        }
#pragma unroll
        for (int j = 0; j < 8; ++j) h1l[u * 20 + w0 + j] = h1r[j];
        __syncthreads();

#pragma unroll
        for (int j = 0; j < 8; ++j) { ar[j] = br2; az[j] = bz2; ai[j] = bni2; ah[j] = bnh2; }
        for (int k = 0; k < 128; ++k) {
            float wr = wih2[k * 384 + u];
            float wz = wih2[k * 384 + 128 + u];
            float wn = wih2[k * 384 + 256 + u];
            const float4 x0 = *(const float4*)&h1l[k * 20 + w0];
            const float4 x1 = *(const float4*)&h1l[k * 20 + w0 + 4];
            float xv[8] = {x0.x, x0.y, x0.z, x0.w, x1.x, x1.y, x1.z, x1.w};
#pragma unroll
            for (int j = 0; j < 8; ++j) {
                ar[j] = fmaf(wr, xv[j], ar[j]);
                az[j] = fmaf(wz, xv[j], az[j]);
                ai[j] = fmaf(wn, xv[j], ai[j]);
            }
        }
        for (int k = 0; k < 128; ++k) {
            float wr = whh2[k * 384 + u];
            float wz = whh2[k * 384 + 128 + u];
            float wn = whh2[k * 384 + 256 + u];
            const float4 x0 = *(const float4*)&h2l[k * 20 + w0];
            const float4 x1 = *(const float4*)&h2l[k * 20 + w0 + 4];
            float xv[8] = {x0.x, x0.y, x0.z, x0.w, x1.x, x1.y, x1.z, x1.w};
#pragma unroll
            for (int j = 0; j < 8; ++j) {
                ar[j] = fmaf(wr, xv[j], ar[j]);
                az[j] = fmaf(wz, xv[j], az[j]);
                ah[j] = fmaf(wn, xv[j], ah[j]);
            }
        }
        __syncthreads();
#pragma unroll
        for (int j = 0; j < 8; ++j) {
            float r = sigm(ar[j]);
            float z = sigm(az[j]);
            float n = tanh_f(ai[j] + r * ah[j]);
            h2r[j] = (1.f - z) * n + z * h2r[j];
        }
#pragma unroll
        for (int j = 0; j < 8; ++j) h2l[u * 20 + w0 + j] = h2r[j];
        __syncthreads();
    }

    for (int idx = tid; idx < 16 * 30; idx += 256) {
        int w = idx / 30, ff = idx - w * 30;
        float acc = b1[ff];
        for (int k = 0; k < 128; ++k) acc = fmaf(h2l[k * 20 + w], W1[ff * 128 + k], acc);
        fbuf[(seq * 2048 + wbase + w) * 32 + ff] = acc;
    }
}

// ------------------------------------------- pairwise sqdist -> E = exp(-D), padded
__global__ __launch_bounds__(256)
void k_pair(const float* __restrict__ fbuf, float* __restrict__ Ep) {
    __shared__ float f1t[64 * 33];
    __shared__ float f2t[64 * 33];
    const int tid = threadIdx.x;
    const int i0 = blockIdx.y * 64, j0 = blockIdx.x * 64;
    for (int e = tid; e < 64 * 32; e += 256) {
        int r = e >> 5, c = e & 31;
        f1t[r * 33 + c] = fbuf[(i0 + r) * 32 + c];
        f2t[r * 33 + c] = fbuf[(2048 + j0 + r) * 32 + c];
    }
    __syncthreads();
    const int tx = tid & 15, ty = tid >> 4;
    float acc[4][4];
#pragma unroll
    for (int r = 0; r < 4; ++r)
#pragma unroll
        for (int c = 0; c < 4; ++c) acc[r][c] = 0.f;
    for (int k = 0; k < 30; ++k) {
        float a[4], b[4];
#pragma unroll
        for (int r = 0; r < 4; ++r) a[r] = f1t[(ty * 4 + r) * 33 + k];
#pragma unroll
        for (int c = 0; c < 4; ++c) b[c] = f2t[(tx * 4 + c) * 33 + k];
#pragma unroll
        for (int r = 0; r < 4; ++r)
#pragma unroll
            for (int c = 0; c < 4; ++c) {
                float d = a[r] - b[c];
                acc[r][c] = fmaf(d, d, acc[r][c]);
            }
    }
#pragma unroll
    for (int r = 0; r < 4; ++r) {
        float4 v = make_float4(__expf(-acc[r][0]), __expf(-acc[r][1]),
                               __expf(-acc[r][2]), __expf(-acc[r][3]));
        *(float4*)&Ep[(size_t)(i0 + ty * 4 + r) * PD_LD + PD_OFF + j0 + tx * 4] = v;
    }
}

// ------------------------------------------- softDTW wavefront, EXP-DOMAIN
// R13 = R12 resubmit (infra failure, no counters). R7 structure (8 blocks x
// 64 lanes x 4 rows, triple-buffered E, 3-deep boundary ring) + two deltas:
//  (1) cell math in fma/off form: off_r = E*(W[r-1]+W[r]) is OFF the serial
//      chain (depends only on prev column), w_r = fma(E, w_{r-1}, off_r) is
//      ONE fma per cell. Per-macro serial chain ~32x4cy instead of
//      ~32x(add3+mul) -- the fitted 400cy/row said this chain dominates.
//  (2) backoff quantum s_sleep(32)->s_sleep(2): 2048cy rounding per
//      frontier contact -> 128cy fine-grained rate matching.
#define DTW_MACRO(CUR, PF, PVC, PVI, M)                                          \
  {                                                                              \
    const int m = (M);                                                           \
    { /* prefetch E tile for macro m+2 */                                        \
        int bs = 8 * (m + 2 - lane);                                             \
        bs = bs < -16 ? -16 : (bs > 2048 ? 2048 : bs);                           \
        _Pragma("unroll")                                                        \
        for (int r = 0; r < 4; ++r) {                                            \
            float4 lo = *(const float4*)(rp[r] + bs);                            \
            float4 hi = *(const float4*)(rp[r] + bs + 4);                        \
            PF[r][0]=lo.x; PF[r][1]=lo.y; PF[r][2]=lo.z; PF[r][3]=lo.w;          \
            PF[r][4]=hi.x; PF[r][5]=hi.y; PF[r][6]=hi.z; PF[r][7]=hi.w;          \
        }                                                                        \
    }                                                                            \
    if (b > 0 && lane == 0) {   /* issue boundary loads for macro m+3 */         \
        _Pragma("unroll")                                                        \
        for (int u = 0; u < 8; ++u) {                                            \
            int jc = 8 * (m + 3) + u; jc = jc > 2047 ? 2047 : jc;                \
            PVI[u] = __hip_atomic_load(&bIn[jc], __ATOMIC_RELAXED,               \
                                       __HIP_MEMORY_SCOPE_AGENT);                \
        }                                                                        \
    }                                                                            \
    float Tw[8];                                                                 \
    _Pragma("unroll")                                                            \
    for (int c = 0; c < 8; ++c) Tw[c] = fexp2(Sc - sIn[c]);                      \
    float Td = fexp2(Sc - carryA);                                               \
    float blog[8];                                                               \
    _Pragma("unroll")                                                            \
    for (int c = 0; c < 8; ++c) {                                                \
        float up0 = Tw[c];                                                       \
        float dg0 = (c == 0) ? Td : Tw[c - 1];                                   \
        float e0 = CUR[0][c], e1 = CUR[1][c], e2 = CUR[2][c], e3 = CUR[3][c];    \
        float o0 = e0 * (dg0 + up0);                                             \
        float o1 = e1 * (W0 + W1);                                               \
        float o2 = e2 * (W1 + W2);                                               \
        float o3 = e3 * (W2 + W3);                                               \
        float w0 = fmaf(e0, W0, o0);                                             \
        float w1 = fmaf(e1, w0, o1);                                             \
        float w2 = fmaf(e2, w1, o2);                                             \
        float w3 = fmaf(e3, w2, o3);                                             \
        W0 = w0; W1 = w1; W2 = w2; W3 = w3;                                      \
        blog[c] = fminf(Sc - flog2(w3), INF2);                                   \
    }                                                                            \
    carryA = sIn[7];                                                             \
    if (lane == 63) {                                                            \
        if (b < 7) {                                                             \
            _Pragma("unroll")                                                    \
            for (int c = 0; c < 8; ++c) {                                        \
                int j = 8 * (m - 63) + c;                                        \
                if (j >= 0 && j < 2048) {                                        \
                    uint64_t pk = ((uint64_t)(uint32_t)j << 32) |                \
                                  (uint64_t)__float_as_uint(blog[c]);            \
                    (void)__hip_atomic_exchange(&bOut[j], pk, __ATOMIC_RELAXED,  \
                                                __HIP_MEMORY_SCOPE_AGENT);       \
                }                                                                \
            }                                                                    \
        } else if (8 * (m - 63) + 7 == 2047) {                                   \
            res = blog[7];                                                       \
        }                                                                        \
    }                                                                            \
    float sh[8];                                                                 \
    _Pragma("unroll")                                                            \
    for (int c = 0; c < 8; ++c) sh[c] = __shfl_up(blog[c], 1);                   \
    if (lane > 0) {                                                              \
        _Pragma("unroll")                                                        \
        for (int c = 0; c < 8; ++c) sIn[c] = sh[c];                              \
    } else if (b == 0) {                                                         \
        _Pragma("unroll")                                                        \
        for (int c = 0; c < 8; ++c) sIn[c] = INF2;                               \
    } else {   /* consume ring slot PVC = boundary for macro m+1 */              \
        bool again = false;                                                      \
        _Pragma("unroll")                                                        \
        for (int u = 0; u < 8; ++u) {                                            \
            int jc = 8 * (m + 1) + u; jc = jc > 2047 ? 2047 : jc;                \
            if ((uint32_t)(PVC[u] >> 32) != (uint32_t)jc) again = true;          \
        }                                                                        \
        while (again) {   /* frontier contact: fine-grained backoff */           \
            __builtin_amdgcn_s_sleep(2);                                         \
            _Pragma("unroll")                                                    \
            for (int u = 0; u < 8; ++u) {                                        \
                int jc = 8 * (m + 1) + u; jc = jc > 2047 ? 2047 : jc;            \
                PVC[u] = __hip_atomic_load(&bIn[jc], __ATOMIC_RELAXED,           \
                                           __HIP_MEMORY_SCOPE_AGENT);            \
            }                                                                    \
            again = false;                                                       \
            _Pragma("unroll")                                                    \
            for (int u = 0; u < 8; ++u) {                                        \
                int jc = 8 * (m + 1) + u; jc = jc > 2047 ? 2047 : jc;            \
                if ((uint32_t)(PVC[u] >> 32) != (uint32_t)jc) again = true;      \
            }                                                                    \
        }                                                                        \
        _Pragma("unroll")                                                        \
        for (int u = 0; u < 8; ++u) sIn[u] = __uint_as_float((uint32_t)PVC[u]);  \
    }                                                                            \
    { /* scale update (uses NEXT macro's incoming mins) */                       \
        float mn = sIn[0];                                                       \
        _Pragma("unroll")                                                        \
        for (int c = 1; c < 8; ++c) mn = fminf(mn, sIn[c]);                      \
        float wmax = fmaxf(fmaxf(W0, W1), fmaxf(W2, W3));                        \
        float Sc_new;                                                            \
        if (wmax > 0.f) {                                                        \
            int e = (int)((__float_as_uint(wmax) >> 23) & 0xFFu) - 127;          \
            Sc_new = fminf(Sc - (float)e, mn + 100.f);                           \
        } else {                                                                 \
            Sc_new = fminf(mn, 1e9f);                                            \
        }                                                                        \
        int dd = (int)fmaxf(fminf(Sc_new - Sc, 999.f), -999.f);                  \
        W0 = ldexpf(W0, dd); W1 = ldexpf(W1, dd);                                \
        W2 = ldexpf(W2, dd); W3 = ldexpf(W3, dd);                                \
        Sc = Sc_new;                                                             \
    }                                                                            \
  }

__global__ __launch_bounds__(64)
void k_dtw(const float* __restrict__ Ep, uint64_t* bndG, float* __restrict__ out) {
    const int b = blockIdx.x;
    const int lane = threadIdx.x;
    const int r0 = b * 256 + lane * 4;
    const uint64_t* bIn = bndG + (size_t)(b - 1) * 2048;
    uint64_t* bOut = bndG + (size_t)b * 2048;

    const float* rp[4];
#pragma unroll
    for (int r = 0; r < 4; ++r) rp[r] = Ep + (size_t)(r0 + r) * PD_LD + PD_OFF;

    float W0 = 0.f, W1 = 0.f, W2 = 0.f, W3 = 0.f;
    float Sc = 0.f;
    float carryA = (b == 0 && lane == 0) ? 0.f : INF2;  // seed: A(-1,-1)=0
    float res = 0.f;
    float sIn[8];
#pragma unroll
    for (int c = 0; c < 8; ++c) sIn[c] = INF2;

    uint64_t pvs0[8], pvs1[8], pvs2[8];

    if (b > 0 && lane == 0) {
        // --- startup SLACK: wait until producer is ~64 cols past our need
        {
            uint64_t p = __hip_atomic_load(&bIn[71], __ATOMIC_RELAXED,
                                           __HIP_MEMORY_SCOPE_AGENT);
            while ((uint32_t)(p >> 32) != 71u) {
                __builtin_amdgcn_s_sleep(8);
                p = __hip_atomic_load(&bIn[71], __ATOMIC_RELAXED,
                                      __HIP_MEMORY_SCOPE_AGENT);
            }
        }
        // --- blocking poll for macro-0 boundary (cols 0..7) + scale seed
        uint64_t pv[8];
        bool again = true;
        while (again) {
#pragma unroll
            for (int u = 0; u < 8; ++u)
                pv[u] = __hip_atomic_load(&bIn[u], __ATOMIC_RELAXED,
                                          __HIP_MEMORY_SCOPE_AGENT);
            again = false;
#pragma unroll
            for (int u = 0; u < 8; ++u)
                if ((uint32_t)(pv[u] >> 32) != (uint32_t)u) again = true;
            if (again) __builtin_amdgcn_s_sleep(2);
        }
        float mn = INF2;
#pragma unroll
        for (int u = 0; u < 8; ++u) {
            sIn[u] = __uint_as_float((uint32_t)pv[u]);
            mn = fminf(mn, sIn[u]);
        }
        Sc = fminf(mn, 1e9f);
        // --- prime ring: targets macro 1 (cols 8..15) and macro 2 (16..23)
#pragma unroll
        for (int u = 0; u < 8; ++u)
            pvs1[u] = __hip_atomic_load(&bIn[8 + u], __ATOMIC_RELAXED,
                                        __HIP_MEMORY_SCOPE_AGENT);
#pragma unroll
        for (int u = 0; u < 8; ++u)
            pvs2[u] = __hip_atomic_load(&bIn[16 + u], __ATOMIC_RELAXED,
                                        __HIP_MEMORY_SCOPE_AGENT);
    }

    float eT0[4][8], eT1[4][8], eT2[4][8];
#pragma unroll
    for (int tt = 0; tt < 2; ++tt) {   // preload tiles for macros 0 and 1
        int bs = 8 * (tt - lane);
        bs = bs < -16 ? -16 : bs;
#pragma unroll
        for (int r = 0; r < 4; ++r) {
            float4 lo = *(const float4*)(rp[r] + bs);
            float4 hi = *(const float4*)(rp[r] + bs + 4);
            float (*dst)[8] = tt ? eT1 : eT0;
            dst[r][0]=lo.x; dst[r][1]=lo.y; dst[r][2]=lo.z; dst[r][3]=lo.w;
            dst[r][4]=hi.x; dst[r][5]=hi.y; dst[r][6]=hi.z; dst[r][7]=hi.w;
        }
    }

    // 321 macro-steps of 8 cols (lane63 hits col 2047 at m=318)
    for (int mm = 0; mm < 321; mm += 3) {
        DTW_MACRO(eT0, eT2, pvs1, pvs0, mm);
        DTW_MACRO(eT1, eT0, pvs2, pvs1, mm + 1);
        DTW_MACRO(eT2, eT1, pvs0, pvs2, mm + 2);
    }

    if (b == 7 && lane == 63) out[0] = res * LN2;   // back to base-e units
}

// ------------------------------------------- launch
extern "C" void kernel_launch(void* const* d_in, const int* in_sizes, int n_in,
                              void* d_out, int out_size, void* d_ws, size_t ws_size,
                              hipStream_t stream) {
    const float* X    = (const float*)d_in[0];
    const float* Y    = (const float*)d_in[1];
    const float* Wih1 = (const float*)d_in[2];
    const float* Whh1 = (const float*)d_in[3];
    const float* bih1 = (const float*)d_in[4];
    const float* bhh1 = (const float*)d_in[5];
    const float* Wih2 = (const float*)d_in[6];
    const float* Whh2 = (const float*)d_in[7];
    const float* bih2 = (const float*)d_in[8];
    const float* bhh2 = (const float*)d_in[9];
    const float* W1   = (const float*)d_in[10];
    const float* b1   = (const float*)d_in[11];
    float* out = (float*)d_out;

    // Layout (floats). wt overlaps Ep's tail (dead after k_gru; k_pair
    // overwrites all of Ep afterwards). ~17.7 MB total.
    float* ws   = (float*)d_ws;
    float* fbuf = ws;                            // 131072 floats
    uint64_t* bndG = (uint64_t*)(ws + 131072);   // 7*2048 u64 = 28672 floats
    float* Ep   = ws + 131072 + 28672;           // 2048*2080 = 4259840 floats
    float* wt   = Ep + 4259840 - 175104;         // overlapped tail

    k_prep<<<684, 256, 0, stream>>>(Wih1, Whh1, Wih2, Whh2, wt);
    k_gru<<<256, 256, 0, stream>>>(X, Y, wt, bih1, bhh1, bih2, bhh2, W1, b1, fbuf);
    k_pair<<<dim3(32, 32), 256, 0, stream>>>(fbuf, Ep);
    k_dtw<<<8, 64, 0, stream>>>(Ep, bndG, out);
}